// Round 12
// baseline (66.281 us; speedup 1.0000x reference)
//
#include <hip/hip_runtime.h>

#define NN 50000
#define NE 400000
#define NG 64
#define NBK 196    // node buckets of 256 (ceil(NN/256))
#define CAP 2560   // csr capacity per bucket (mean 2048, sd ~45; +11 sigma)
#define SB 98      // scatter blocks
#define EPB 4096   // edges per scatter block (SB*EPB >= NE)
#define NGB 782    // gather grid: ceil(NN*4/256)

typedef unsigned int uint32;
typedef unsigned short uint16;

// ---------------------------------------------------------------------------
// Linear-GCN collapse (validated rounds 1-11, absmax <= 2e-6):
//   x3 = A^3 X (W1W2W3) + (A^2 1)(b1^T W2 W3) + (A 1)(b2^T W3) + 1 b3^T
// with A = D^-1/2 (Adj+I) D^-1/2;  z = deg^-1/2 .* y, z' = (z+sum_in z)/deg.
// Round 12: round-11 (61.9 us) + k_final merged into k_g3pf with the FIXED
// tail: relaxed ticket (no fences — round-8 lesson), and the last block
// stages pooled[512] into LDS with 2 atomic loads/thread instead of
// round-10's 288 serialized uncached loads/thread (the 10.6 us tail).
// 6 dispatches, every kernel at full per-kernel occupancy.
// ---------------------------------------------------------------------------

static __device__ __forceinline__ float wsum(float v) {
#pragma unroll
  for (int o = 32; o > 0; o >>= 1) v += __shfl_xor(v, o, 64);
  return v;
}

// block 0: zero rsv/pooled/done; block 1: collapsed weight products.
__global__ void __launch_bounds__(256) k_init(
    const float* __restrict__ W1, const float* __restrict__ b1,
    const float* __restrict__ W2, const float* __restrict__ b2,
    const float* __restrict__ W3, float* __restrict__ W123,
    float* __restrict__ bW23, float* __restrict__ bW3,
    uint32* __restrict__ rsv, float* __restrict__ pooled,
    uint32* __restrict__ done) {
  int t = threadIdx.x;
  if (blockIdx.x == 0) {
    rsv[t] = 0u;
    pooled[t] = 0.f;
    pooled[256 + t] = 0.f;
    if (t == 0) *done = 0u;
    return;
  }
  __shared__ float w12[144];
  __shared__ float t48[48];
  if (t < 144) {
    int i = t / 48, k = t % 48;
    float s = 0.f;
    for (int j = 0; j < 24; ++j) s += W1[i * 24 + j] * W2[j * 48 + k];
    w12[t] = s;
  }
  if (t < 48) {
    float s = 0.f;
    for (int j = 0; j < 24; ++j) s += b1[j] * W2[j * 48 + t];
    t48[t] = s;
  }
  __syncthreads();
  if (t < 192) {
    float a0 = 0, a1 = 0, a2 = 0, ab = 0, ab3 = 0;
    for (int k = 0; k < 48; ++k) {
      float w3 = W3[k * 192 + t];
      a0 += w12[k] * w3;
      a1 += w12[48 + k] * w3;
      a2 += w12[96 + k] * w3;
      ab += t48[k] * w3;
      ab3 += b2[k] * w3;
    }
    W123[t] = a0;
    W123[192 + t] = a1;
    W123[384 + t] = a2;
    bW23[t] = ab;
    bW3[t] = ab3;
  }
}

// bucket-partition edges into fixed-capacity regions: LDS counts, one global
// reservation per (block,bucket), LDS-cursor placement at b*CAP + base.
// ebuf entry = src | (dst&255)<<16.
__global__ void __launch_bounds__(256) k_bscat(const int* __restrict__ src,
                                               const int* __restrict__ dst,
                                               uint32* __restrict__ rsv,
                                               uint32* __restrict__ ebuf) {
  __shared__ uint32 cnt[256];
  __shared__ uint32 base[256];
  int t = threadIdx.x;
  cnt[t] = 0u;
  __syncthreads();
  uint32 pk[16];
  uint32 bk[16];
  int e0 = blockIdx.x * EPB + t;
#pragma unroll
  for (int k = 0; k < 16; ++k) {
    int e = e0 + k * 256;
    uint32 b = 0xFFFFFFFFu, p = 0u;
    if (e < NE) {
      uint32 s = (uint32)src[e], d = (uint32)dst[e];
      b = d >> 8;
      p = s | ((d & 255u) << 16);
      atomicAdd(&cnt[b], 1u);
    }
    pk[k] = p;
    bk[k] = b;
  }
  __syncthreads();
  {
    uint32 c = cnt[t];
    base[t] = c ? (t * CAP + atomicAdd(&rsv[t], c)) : 0u;
    cnt[t] = 0u;
  }
  __syncthreads();
#pragma unroll
  for (int k = 0; k < 16; ++k) {
    if (bk[k] != 0xFFFFFFFFu) {
      uint32 slot = base[bk[k]] + atomicAdd(&cnt[bk[k]], 1u);
      ebuf[slot] = pk[k];
    }
  }
}

// one block per bucket: LDS degree count + scan over ebuf[b*CAP .. +rsv[b]) ->
// offse (start,end) / csr (u16 src ids); drr = (1/deg, sqrt(deg));
// z0 = [x|1] * deg^-1/2 built directly from x into A.
__global__ void __launch_bounds__(256) k_csr(const uint32* __restrict__ rsv,
                                             const uint32* __restrict__ ebuf,
                                             const float* __restrict__ x,
                                             uint16* __restrict__ csr,
                                             uint2* __restrict__ offse,
                                             float2* __restrict__ drr,
                                             float* __restrict__ A) {
  __shared__ uint32 cnt[256];
  __shared__ uint32 scn[256];
  int b = blockIdx.x, t = threadIdx.x;
  uint32 lo = (uint32)b * CAP;
  uint32 hi = lo + rsv[b];
  cnt[t] = 0u;
  __syncthreads();
  for (uint32 i = lo + t; i < hi; i += 256) atomicAdd(&cnt[ebuf[i] >> 16], 1u);
  __syncthreads();
  uint32 c = cnt[t];
  scn[t] = c;
  __syncthreads();
  for (int o = 1; o < 256; o <<= 1) {
    uint32 u = (t >= o) ? scn[t - o] : 0u;
    __syncthreads();
    scn[t] += u;
    __syncthreads();
  }
  uint32 excl = scn[t] - c;
  cnt[t] = excl;  // becomes local cursor
  int n = b * 256 + t;
  if (n < NN) {
    uint2 oe;
    oe.x = lo + excl;
    oe.y = lo + excl + c;
    offse[n] = oe;
    float deg = (float)(c + 1u);
    float ds = rsqrtf(deg);
    float2 dr;
    dr.x = 1.0f / deg;
    dr.y = sqrtf(deg);
    drr[n] = dr;
    float4 v4;
    v4.x = x[3 * n + 0] * ds;
    v4.y = x[3 * n + 1] * ds;
    v4.z = x[3 * n + 2] * ds;
    v4.w = ds;
    reinterpret_cast<float4*>(A)[n] = v4;
  }
  __syncthreads();
  for (uint32 i = lo + t; i < hi; i += 256) {
    uint32 p = ebuf[i];
    uint32 slot = atomicAdd(&cnt[p >> 16], 1u);
    csr[lo + slot] = (uint16)p;
  }
}

// 4 lanes per node: z'[n] = dis2[n] * (z[n] + sum_{s in csr[start:end]} z[s])
__global__ void k_gather(const uint2* __restrict__ offse,
                         const uint16* __restrict__ csr,
                         const float2* __restrict__ drr,
                         const float* __restrict__ zin, float* __restrict__ zout) {
  int tid = blockIdx.x * blockDim.x + threadIdx.x;
  int n = tid >> 2, ln = tid & 3;
  if (n >= NN) return;
  uint2 oe = offse[n];
  float4 acc = make_float4(0.f, 0.f, 0.f, 0.f);
  for (uint32 i = oe.x + ln; i < oe.y; i += 4) {
    uint32 s = csr[i];
    float4 v = reinterpret_cast<const float4*>(zin)[s];
    acc.x += v.x; acc.y += v.y; acc.z += v.z; acc.w += v.w;
  }
#pragma unroll
  for (int o = 1; o < 4; o <<= 1) {
    acc.x += __shfl_xor(acc.x, o, 64);
    acc.y += __shfl_xor(acc.y, o, 64);
    acc.z += __shfl_xor(acc.z, o, 64);
    acc.w += __shfl_xor(acc.w, o, 64);
  }
  if (ln == 0) {
    float4 zs = reinterpret_cast<const float4*>(zin)[n];
    float w = drr[n].x;
    float4 o4;
    o4.x = (acc.x + zs.x) * w;
    o4.y = (acc.y + zs.y) * w;
    o4.z = (acc.z + zs.z) * w;
    o4.w = (acc.w + zs.w) * w;
    reinterpret_cast<float4*>(zout)[n] = o4;
  }
}

// third gather fused with pooling; relaxed ticket; LAST block stages pooled
// into LDS (2 atomic loads/thread) and does the 64x192 final combine.
__global__ void __launch_bounds__(256) k_g3pf(
    const uint2* __restrict__ offse, const uint16* __restrict__ csr,
    const float2* __restrict__ drr, const int* __restrict__ batch,
    const float* __restrict__ B,   // z1
    const float* __restrict__ C2,  // z2
    float* __restrict__ pooled, uint32* __restrict__ done,
    const float* __restrict__ W123, const float* __restrict__ bW23,
    const float* __restrict__ bW3, const float* __restrict__ b3,
    float* __restrict__ out) {
  int tid = blockIdx.x * blockDim.x + threadIdx.x;
  int n = tid >> 2, ln = tid & 3;
  if (n < NN) {  // wave-aligned: boundary 200000 = 3125 * 64
    uint2 oe = offse[n];
    float ax = 0.f, ay = 0.f, az = 0.f;
    for (uint32 i = oe.x + ln; i < oe.y; i += 4) {
      uint32 s = csr[i];
      float4 v = reinterpret_cast<const float4*>(C2)[s];
      ax += v.x; ay += v.y; az += v.z;
    }
#pragma unroll
    for (int o = 1; o < 4; o <<= 1) {
      ax += __shfl_xor(ax, o, 64);
      ay += __shfl_xor(ay, o, 64);
      az += __shfl_xor(az, o, 64);
    }
    int g = batch[n];
    float vx = 0, vy = 0, vz = 0, v1 = 0, v2 = 0, cc = 0;
    if (ln == 0) {
      float4 zs = reinterpret_cast<const float4*>(C2)[n];
      float2 dr = drr[n];
      float rr = dr.y;
      float wr = dr.x * rr;
      vx = (ax + zs.x) * wr;
      vy = (ay + zs.y) * wr;
      vz = (az + zs.z) * wr;
      v1 = zs.w * rr;          // z2.w * r = (A^2 1)[n]
      v2 = B[4 * n + 3] * rr;  // z1.w * r = (A 1)[n]
      cc = 1.0f;
    }
    int g0 = __shfl(g, 0, 64);
    bool uni = __all(g == g0);
    if (uni) {
      float sx = wsum(vx), sy = wsum(vy), sz = wsum(vz);
      float s1 = wsum(v1), s2 = wsum(v2), sc = wsum(cc);
      if ((threadIdx.x & 63) == 0) {
        float* p = pooled + 8 * g0;
        atomicAdd(p + 0, sx); atomicAdd(p + 1, sy); atomicAdd(p + 2, sz);
        atomicAdd(p + 3, s1); atomicAdd(p + 4, s2); atomicAdd(p + 5, sc);
      }
    } else if (ln == 0) {
      float* p = pooled + 8 * g;
      atomicAdd(p + 0, vx); atomicAdd(p + 1, vy); atomicAdd(p + 2, vz);
      atomicAdd(p + 3, v1); atomicAdd(p + 4, v2); atomicAdd(p + 5, cc);
    }
  }
  // relaxed ticket: __syncthreads drains vmcnt (adds acked at L3 coherence
  // point) before the fetch_add; no cache-maintenance instructions emitted.
  __shared__ float sp[512];
  __shared__ int lastf;
  __syncthreads();
  if (threadIdx.x == 0) {
    uint32 d = __hip_atomic_fetch_add(done, 1u, __ATOMIC_RELAXED,
                                      __HIP_MEMORY_SCOPE_AGENT);
    lastf = (d == (uint32)(gridDim.x - 1)) ? 1 : 0;
  }
  __syncthreads();
  if (lastf) {
    int t = threadIdx.x;
    sp[t] = __hip_atomic_load(pooled + t, __ATOMIC_RELAXED,
                              __HIP_MEMORY_SCOPE_AGENT);
    sp[256 + t] = __hip_atomic_load(pooled + 256 + t, __ATOMIC_RELAXED,
                                    __HIP_MEMORY_SCOPE_AGENT);
    __syncthreads();
    for (int i = t; i < NG * 192; i += 256) {
      int g = i / 192, l = i - g * 192;
      const float* p = sp + 8 * g;
      float ic = 1.0f / fmaxf(p[5], 1.0f);
      out[i] = (p[0] * W123[l] + p[1] * W123[192 + l] + p[2] * W123[384 + l] +
                p[3] * bW23[l] + p[4] * bW3[l]) * ic + b3[l];
    }
  }
}

extern "C" void kernel_launch(void* const* d_in, const int* in_sizes, int n_in,
                              void* d_out, int out_size, void* d_ws, size_t ws_size,
                              hipStream_t stream) {
  const float* x = (const float*)d_in[0];   // [NN,3]
  const int* edges = (const int*)d_in[1];   // [2,NE]
  const int* batch = (const int*)d_in[2];   // [NN]
  const float* W1 = (const float*)d_in[3];
  const float* b1 = (const float*)d_in[4];
  const float* W2 = (const float*)d_in[5];
  const float* b2 = (const float*)d_in[6];
  const float* W3 = (const float*)d_in[7];
  const float* b3 = (const float*)d_in[8];
  float* out = (float*)d_out;

  const int* src = edges;
  const int* dst = edges + NE;

  float* ws = (float*)d_ws;
  uint32* rsv = (uint32*)ws;                 // [256] bucket reservation cursors
  uint2* offse = (uint2*)(ws + 256);         // [NN] {start,end}
  float2* drr = (float2*)(ws + 100256);      // [NN] {1/deg, sqrt(deg)}
  float* A = ws + 200256;                    // [NN*4]  z0
  float* B = ws + 400256;                    // [NN*4]  z1
  float* C2 = ws + 600256;                   // [NN*4]  z2
  uint32* ebuf = (uint32*)(ws + 800256);     // [NBK*CAP = 501760]
  uint16* csr = (uint16*)(ws + 1302016);     // [NBK*CAP] u16 (250880 words)
  float* pooled = ws + 1552896;              // [512]
  float* W123 = ws + 1553408;                // [576]
  float* bW23 = ws + 1553984;                // [192]
  float* bW3 = ws + 1554176;                 // [192]
  uint32* done = (uint32*)(ws + 1554368);    // [1]

  dim3 b256(256);

  k_init<<<2, b256, 0, stream>>>(W1, b1, W2, b2, W3, W123, bW23, bW3,
                                 rsv, pooled, done);
  k_bscat<<<SB, b256, 0, stream>>>(src, dst, rsv, ebuf);
  k_csr<<<NBK, b256, 0, stream>>>(rsv, ebuf, x, csr, offse, drr, A);

  k_gather<<<NGB, b256, 0, stream>>>(offse, csr, drr, A, B);   // z0 -> z1
  k_gather<<<NGB, b256, 0, stream>>>(offse, csr, drr, B, C2);  // z1 -> z2
  k_g3pf<<<NGB, b256, 0, stream>>>(offse, csr, drr, batch, B, C2, pooled, done,
                                   W123, bW23, bW3, b3, out);
}

// Round 13
// 61.598 us; speedup vs baseline: 1.0760x; 1.0760x over previous
//
#include <hip/hip_runtime.h>

#define NN 50000
#define NE 400000
#define NG 64
#define NBK 196    // node buckets of 256 (ceil(NN/256))
#define CAP 2560   // csr capacity per bucket (mean 2048, sd ~45; +11 sigma)
#define SB 98      // scatter blocks
#define EPB 4096   // edges per scatter block (SB*EPB >= NE)
#define NGB 782    // gather grid: ceil(NN*4/256)

typedef unsigned int uint32;
typedef unsigned short uint16;

// ---------------------------------------------------------------------------
// Linear-GCN collapse (validated rounds 1-12, absmax <= 2e-6):
//   x3 = A^3 X (W1W2W3) + (A^2 1)(b1^T W2 W3) + (A 1)(b2^T W3) + 1 b3^T
// with A = D^-1/2 (Adj+I) D^-1/2;  z = deg^-1/2 .* y, z' = (z+sum_in z)/deg.
// Round 13 (FINAL): revert to round 11 — the verified best (61.9 us; round 7
// twin at 61.3). Refuted-with-mechanism and not retried:
//  - cooperative mega-kernel (r5): 1 wave/SIMD occupancy -> 3.4x slower;
//  - in-kernel completion tracking (r8/r10/r12): per-block agent-scope RMW
//    ticket costs 4-38 us vs the 3.5 us dispatch boundary it replaces;
//  - merged two-pass bscat + sparse csr scan (r9): -12 us of real work.
// Floor: ~37 us L2-latency-bound sparse work + ~24 us launch gaps over a
// 7-deep true dependency chain. HBM ~1%, VALU ~5% — launch-latency-bound.
// ---------------------------------------------------------------------------

static __device__ __forceinline__ float wsum(float v) {
#pragma unroll
  for (int o = 32; o > 0; o >>= 1) v += __shfl_xor(v, o, 64);
  return v;
}

// block 0: zero rsv/pooled; block 1: collapsed weight products.
__global__ void __launch_bounds__(256) k_init(
    const float* __restrict__ W1, const float* __restrict__ b1,
    const float* __restrict__ W2, const float* __restrict__ b2,
    const float* __restrict__ W3, float* __restrict__ W123,
    float* __restrict__ bW23, float* __restrict__ bW3,
    uint32* __restrict__ rsv, float* __restrict__ pooled) {
  int t = threadIdx.x;
  if (blockIdx.x == 0) {
    rsv[t] = 0u;
    pooled[t] = 0.f;
    pooled[256 + t] = 0.f;
    return;
  }
  __shared__ float w12[144];
  __shared__ float t48[48];
  if (t < 144) {
    int i = t / 48, k = t % 48;
    float s = 0.f;
    for (int j = 0; j < 24; ++j) s += W1[i * 24 + j] * W2[j * 48 + k];
    w12[t] = s;
  }
  if (t < 48) {
    float s = 0.f;
    for (int j = 0; j < 24; ++j) s += b1[j] * W2[j * 48 + t];
    t48[t] = s;
  }
  __syncthreads();
  if (t < 192) {
    float a0 = 0, a1 = 0, a2 = 0, ab = 0, ab3 = 0;
    for (int k = 0; k < 48; ++k) {
      float w3 = W3[k * 192 + t];
      a0 += w12[k] * w3;
      a1 += w12[48 + k] * w3;
      a2 += w12[96 + k] * w3;
      ab += t48[k] * w3;
      ab3 += b2[k] * w3;
    }
    W123[t] = a0;
    W123[192 + t] = a1;
    W123[384 + t] = a2;
    bW23[t] = ab;
    bW3[t] = ab3;
  }
}

// bucket-partition edges into fixed-capacity regions: LDS counts, one global
// reservation per (block,bucket), LDS-cursor placement at b*CAP + base.
// ebuf entry = src | (dst&255)<<16.
__global__ void __launch_bounds__(256) k_bscat(const int* __restrict__ src,
                                               const int* __restrict__ dst,
                                               uint32* __restrict__ rsv,
                                               uint32* __restrict__ ebuf) {
  __shared__ uint32 cnt[256];
  __shared__ uint32 base[256];
  int t = threadIdx.x;
  cnt[t] = 0u;
  __syncthreads();
  uint32 pk[16];
  uint32 bk[16];
  int e0 = blockIdx.x * EPB + t;
#pragma unroll
  for (int k = 0; k < 16; ++k) {
    int e = e0 + k * 256;
    uint32 b = 0xFFFFFFFFu, p = 0u;
    if (e < NE) {
      uint32 s = (uint32)src[e], d = (uint32)dst[e];
      b = d >> 8;
      p = s | ((d & 255u) << 16);
      atomicAdd(&cnt[b], 1u);
    }
    pk[k] = p;
    bk[k] = b;
  }
  __syncthreads();
  {
    uint32 c = cnt[t];
    base[t] = c ? (t * CAP + atomicAdd(&rsv[t], c)) : 0u;
    cnt[t] = 0u;
  }
  __syncthreads();
#pragma unroll
  for (int k = 0; k < 16; ++k) {
    if (bk[k] != 0xFFFFFFFFu) {
      uint32 slot = base[bk[k]] + atomicAdd(&cnt[bk[k]], 1u);
      ebuf[slot] = pk[k];
    }
  }
}

// one block per bucket: LDS degree count + scan over ebuf[b*CAP .. +rsv[b]) ->
// offse (start,end) / csr (u16 src ids); drr = (1/deg, sqrt(deg));
// z0 = [x|1] * deg^-1/2 built directly from x into A.
__global__ void __launch_bounds__(256) k_csr(const uint32* __restrict__ rsv,
                                             const uint32* __restrict__ ebuf,
                                             const float* __restrict__ x,
                                             uint16* __restrict__ csr,
                                             uint2* __restrict__ offse,
                                             float2* __restrict__ drr,
                                             float* __restrict__ A) {
  __shared__ uint32 cnt[256];
  __shared__ uint32 scn[256];
  int b = blockIdx.x, t = threadIdx.x;
  uint32 lo = (uint32)b * CAP;
  uint32 hi = lo + rsv[b];
  cnt[t] = 0u;
  __syncthreads();
  for (uint32 i = lo + t; i < hi; i += 256) atomicAdd(&cnt[ebuf[i] >> 16], 1u);
  __syncthreads();
  uint32 c = cnt[t];
  scn[t] = c;
  __syncthreads();
  for (int o = 1; o < 256; o <<= 1) {
    uint32 u = (t >= o) ? scn[t - o] : 0u;
    __syncthreads();
    scn[t] += u;
    __syncthreads();
  }
  uint32 excl = scn[t] - c;
  cnt[t] = excl;  // becomes local cursor
  int n = b * 256 + t;
  if (n < NN) {
    uint2 oe;
    oe.x = lo + excl;
    oe.y = lo + excl + c;
    offse[n] = oe;
    float deg = (float)(c + 1u);
    float ds = rsqrtf(deg);
    float2 dr;
    dr.x = 1.0f / deg;
    dr.y = sqrtf(deg);
    drr[n] = dr;
    float4 v4;
    v4.x = x[3 * n + 0] * ds;
    v4.y = x[3 * n + 1] * ds;
    v4.z = x[3 * n + 2] * ds;
    v4.w = ds;
    reinterpret_cast<float4*>(A)[n] = v4;
  }
  __syncthreads();
  for (uint32 i = lo + t; i < hi; i += 256) {
    uint32 p = ebuf[i];
    uint32 slot = atomicAdd(&cnt[p >> 16], 1u);
    csr[lo + slot] = (uint16)p;
  }
}

// 4 lanes per node: z'[n] = dis2[n] * (z[n] + sum_{s in csr[start:end]} z[s])
__global__ void k_gather(const uint2* __restrict__ offse,
                         const uint16* __restrict__ csr,
                         const float2* __restrict__ drr,
                         const float* __restrict__ zin, float* __restrict__ zout) {
  int tid = blockIdx.x * blockDim.x + threadIdx.x;
  int n = tid >> 2, ln = tid & 3;
  if (n >= NN) return;
  uint2 oe = offse[n];
  float4 acc = make_float4(0.f, 0.f, 0.f, 0.f);
  for (uint32 i = oe.x + ln; i < oe.y; i += 4) {
    uint32 s = csr[i];
    float4 v = reinterpret_cast<const float4*>(zin)[s];
    acc.x += v.x; acc.y += v.y; acc.z += v.z; acc.w += v.w;
  }
#pragma unroll
  for (int o = 1; o < 4; o <<= 1) {
    acc.x += __shfl_xor(acc.x, o, 64);
    acc.y += __shfl_xor(acc.y, o, 64);
    acc.z += __shfl_xor(acc.z, o, 64);
    acc.w += __shfl_xor(acc.w, o, 64);
  }
  if (ln == 0) {
    float4 zs = reinterpret_cast<const float4*>(zin)[n];
    float w = drr[n].x;
    float4 o4;
    o4.x = (acc.x + zs.x) * w;
    o4.y = (acc.y + zs.y) * w;
    o4.z = (acc.z + zs.z) * w;
    o4.w = (acc.w + zs.w) * w;
    reinterpret_cast<float4*>(zout)[n] = o4;
  }
}

// third gather pass fused with pooling: z3 stays in registers.
// pooled[g] += (z3.xyz * r, z2.w * r, z1.w * r, 1) per node.
__global__ void k_g3p(const uint2* __restrict__ offse,
                      const uint16* __restrict__ csr,
                      const float2* __restrict__ drr,
                      const int* __restrict__ batch,
                      const float* __restrict__ B,   // z1
                      const float* __restrict__ C2,  // z2
                      float* __restrict__ pooled) {
  int tid = blockIdx.x * blockDim.x + threadIdx.x;
  int n = tid >> 2, ln = tid & 3;
  if (n >= NN) return;
  uint2 oe = offse[n];
  float ax = 0.f, ay = 0.f, az = 0.f;
  for (uint32 i = oe.x + ln; i < oe.y; i += 4) {
    uint32 s = csr[i];
    float4 v = reinterpret_cast<const float4*>(C2)[s];
    ax += v.x; ay += v.y; az += v.z;
  }
#pragma unroll
  for (int o = 1; o < 4; o <<= 1) {
    ax += __shfl_xor(ax, o, 64);
    ay += __shfl_xor(ay, o, 64);
    az += __shfl_xor(az, o, 64);
  }
  int g = batch[n];
  float vx = 0, vy = 0, vz = 0, v1 = 0, v2 = 0, cc = 0;
  if (ln == 0) {
    float4 zs = reinterpret_cast<const float4*>(C2)[n];
    float2 dr = drr[n];
    float rr = dr.y;
    float wr = dr.x * rr;
    vx = (ax + zs.x) * wr;
    vy = (ay + zs.y) * wr;
    vz = (az + zs.z) * wr;
    v1 = zs.w * rr;          // z2.w * r = (A^2 1)[n]
    v2 = B[4 * n + 3] * rr;  // z1.w * r = (A 1)[n]
    cc = 1.0f;
  }
  int g0 = __shfl(g, 0, 64);
  bool uni = __all(g == g0);
  if (uni) {
    float sx = wsum(vx), sy = wsum(vy), sz = wsum(vz);
    float s1 = wsum(v1), s2 = wsum(v2), sc = wsum(cc);
    if ((threadIdx.x & 63) == 0) {
      float* p = pooled + 8 * g0;
      atomicAdd(p + 0, sx); atomicAdd(p + 1, sy); atomicAdd(p + 2, sz);
      atomicAdd(p + 3, s1); atomicAdd(p + 4, s2); atomicAdd(p + 5, sc);
    }
  } else if (ln == 0) {
    float* p = pooled + 8 * g;
    atomicAdd(p + 0, vx); atomicAdd(p + 1, vy); atomicAdd(p + 2, vz);
    atomicAdd(p + 3, v1); atomicAdd(p + 4, v2); atomicAdd(p + 5, cc);
  }
}

__global__ void k_final(const float* __restrict__ pooled, const float* __restrict__ W123,
                        const float* __restrict__ bW23, const float* __restrict__ bW3,
                        const float* __restrict__ b3, float* __restrict__ out) {
  int g = blockIdx.x;   // 64
  int l = threadIdx.x;  // 192
  const float* p = pooled + 8 * g;
  float ic = 1.0f / fmaxf(p[5], 1.0f);
  float sx = p[0] * ic, sy = p[1] * ic, sz = p[2] * ic;
  float v1 = p[3] * ic, v2 = p[4] * ic;
  out[g * 192 + l] = sx * W123[l] + sy * W123[192 + l] + sz * W123[384 + l] +
                     v1 * bW23[l] + v2 * bW3[l] + b3[l];
}

extern "C" void kernel_launch(void* const* d_in, const int* in_sizes, int n_in,
                              void* d_out, int out_size, void* d_ws, size_t ws_size,
                              hipStream_t stream) {
  const float* x = (const float*)d_in[0];   // [NN,3]
  const int* edges = (const int*)d_in[1];   // [2,NE]
  const int* batch = (const int*)d_in[2];   // [NN]
  const float* W1 = (const float*)d_in[3];
  const float* b1 = (const float*)d_in[4];
  const float* W2 = (const float*)d_in[5];
  const float* b2 = (const float*)d_in[6];
  const float* W3 = (const float*)d_in[7];
  const float* b3 = (const float*)d_in[8];
  float* out = (float*)d_out;

  const int* src = edges;
  const int* dst = edges + NE;

  float* ws = (float*)d_ws;
  uint32* rsv = (uint32*)ws;                 // [256] bucket reservation cursors
  uint2* offse = (uint2*)(ws + 256);         // [NN] {start,end}
  float2* drr = (float2*)(ws + 100256);      // [NN] {1/deg, sqrt(deg)}
  float* A = ws + 200256;                    // [NN*4]  z0
  float* B = ws + 400256;                    // [NN*4]  z1
  float* C2 = ws + 600256;                   // [NN*4]  z2
  uint32* ebuf = (uint32*)(ws + 800256);     // [NBK*CAP = 501760]
  uint16* csr = (uint16*)(ws + 1302016);     // [NBK*CAP] u16 (250880 words)
  float* pooled = ws + 1552896;              // [512]
  float* W123 = ws + 1553408;                // [576]
  float* bW23 = ws + 1553984;                // [192]
  float* bW3 = ws + 1554176;                 // [192]

  dim3 b256(256);

  k_init<<<2, b256, 0, stream>>>(W1, b1, W2, b2, W3, W123, bW23, bW3, rsv, pooled);
  k_bscat<<<SB, b256, 0, stream>>>(src, dst, rsv, ebuf);
  k_csr<<<NBK, b256, 0, stream>>>(rsv, ebuf, x, csr, offse, drr, A);

  k_gather<<<NGB, b256, 0, stream>>>(offse, csr, drr, A, B);   // z0 -> z1
  k_gather<<<NGB, b256, 0, stream>>>(offse, csr, drr, B, C2);  // z1 -> z2
  k_g3p<<<NGB, b256, 0, stream>>>(offse, csr, drr, batch, B, C2, pooled);

  k_final<<<NG, 192, 0, stream>>>(pooled, W123, bW23, bW3, b3, out);
}